// Round 2
// baseline (9786.144 us; speedup 1.0000x reference)
//
#include <hip/hip_runtime.h>
#include <stdint.h>

// LSTM(relu) persistent kernel v2: B=64,S=1024,F=128,H=512.
// 4 batch-groups x 8 unit-wgs = 32 wgs, 512 threads (8 waves) each.
// U/W live in REGISTERS as operand-swapped MFMA A-frags (z^T = U^T * h^T):
//   per wave: 64 units? no -> 8 units = 2 D-tiles, 20 A-frags each (160 VGPR).
// Swapped D-layout: lane = (batch row, unit), regs 0..3 = gates i,f,g,o ->
// gate combine is register-local, no shuffles, no LDS anywhere.
// h exchanged via double-buffered global bf16 buffer + per-wg release flags
// (64B apart); wave 0 polls all 8 group flags in parallel (lane-per-flag).

#define B_ 64
#define S_ 1024
#define F_ 128
#define H_ 512
#define G4_ 2048
#define GROUPS 4
#define WGPG 8          // wgs per batch group
#define BG_ 16          // batch rows per group
#define WAVES 8
#define UW 8            // units per wave
#define TILES 2         // 4 units per D-tile
#define KH 16           // h@U K-steps (512/32)
#define KX 4            // x@W K-steps (128/32)
#define KT 20
#define HBUF_ELEMS (B_ * H_)   // one h buffer: 32768 bf16

typedef __attribute__((ext_vector_type(8))) short short8;  // 8 x bf16
typedef __attribute__((ext_vector_type(4))) float f32x4;

__device__ __forceinline__ unsigned short f2bf(float f) {
  union { float f; unsigned u; } v; v.f = f;
  unsigned u = v.u + 0x7fffu + ((v.u >> 16) & 1u);   // RNE
  return (unsigned short)(u >> 16);
}

__device__ __forceinline__ short8 pack2(f32x4 a, f32x4 b) {
  short8 r;
#pragma unroll
  for (int i = 0; i < 4; ++i) r[i] = (short)f2bf(a[i]);
#pragma unroll
  for (int i = 0; i < 4; ++i) r[4 + i] = (short)f2bf(b[i]);
  return r;
}

__global__ __launch_bounds__(512) void lstm_pers(
    const float* __restrict__ x, const float* __restrict__ W,
    const float* __restrict__ U, const float* __restrict__ bias,
    float* __restrict__ out, unsigned int* flags, unsigned short* hbuf) {

  const int tid  = threadIdx.x;
  const int lane = tid & 63;
  const int w    = tid >> 6;           // wave 0..7
  const int l15  = lane & 15;
  const int l4   = lane >> 4;          // 0..3
  const int koff = l4 * 8;

  const int blk   = blockIdx.x;        // 0..31
  const int grp   = blk & 3;           // batch group
  const int j     = blk >> 2;          // wg-in-group 0..7
  const int u0    = j * (WAVES * UW) + w * UW;   // this wave's unit base
  const int bbase = grp * BG_;

  unsigned int* gflags = flags + (size_t)grp * WGPG * 16;  // 64B-spaced flags
  unsigned int* myflag = gflags + j * 16;

  // ---- one-time: U^T / W^T A-fragments into registers ----
  // A-frag lane layout: lane holds A[m = l15][k = koff + jj],
  // A[m][k] = U[k][zcol(m)], zcol(m) = (m&3)*H + unit, unit = u0+tl*4+(m>>2)
  const int gate_a = l15 & 3;
  const int usub_a = l15 >> 2;
  short8 au[TILES][KT];
#pragma unroll
  for (int tl = 0; tl < TILES; ++tl) {
    const int zcol = gate_a * H_ + u0 + tl * 4 + usub_a;
#pragma unroll
    for (int ks = 0; ks < KT; ++ks) {
      short8 v;
#pragma unroll
      for (int jj = 0; jj < 8; ++jj) {
        const int k = ks * 32 + koff + jj;
        const float f = (ks < KH) ? U[(size_t)k * G4_ + zcol]
                                  : W[(size_t)(k - H_) * G4_ + zcol];
        v[jj] = (short)f2bf(f);
      }
      au[tl][ks] = v;
    }
  }

  // bias per (tile, gate) for the D-side lane mapping (unit uses l4)
  float bias_r[TILES][4];
#pragma unroll
  for (int tl = 0; tl < TILES; ++tl)
#pragma unroll
    for (int g = 0; g < 4; ++g)
      bias_r[tl][g] = bias[g * H_ + u0 + tl * 4 + l4];

  float cst[TILES] = {0.f, 0.f};       // c-state: one (row,unit) per lane/tile

  const float* xrow = x + ((size_t)(bbase + l15) * S_) * F_ + koff;
  const unsigned short* hrow0 = hbuf + (size_t)(bbase + l15) * H_ + koff;

  for (int t = 0; t < S_; ++t) {
    // ---- issue x loads first (independent of h; overlap poll latency) ----
    const float* xt = xrow + (size_t)t * F_;
    f32x4 xa[KX], xb[KX];
#pragma unroll
    for (int q = 0; q < KX; ++q) {
      xa[q] = *(const f32x4*)(xt + q * 32);
      xb[q] = *(const f32x4*)(xt + q * 32 + 4);
    }

    short8 bh[KH];
    if (t > 0) {
      // ---- wait for all 8 wgs of this group to have published h(t-1) ----
      if (w == 0) {
        unsigned int* pf = gflags + (lane & 7) * 16;
        const unsigned tgt = (unsigned)t;
        while (true) {
          unsigned v = __hip_atomic_load(pf, __ATOMIC_RELAXED, __HIP_MEMORY_SCOPE_AGENT);
          if (__all((int)(v >= tgt))) break;
        }
        (void)__hip_atomic_load(myflag, __ATOMIC_ACQUIRE, __HIP_MEMORY_SCOPE_AGENT);
      }
      __syncthreads();
      // ---- issue all h B-frag loads (in flight during x@W MFMAs) ----
      const unsigned short* hr = hrow0 + (size_t)(t & 1) * HBUF_ELEMS;
#pragma unroll
      for (int ks = 0; ks < KH; ++ks)
        bh[ks] = *(const short8*)(hr + ks * 32);
    }

    // ---- acc = bias ----
    f32x4 acc[TILES];
#pragma unroll
    for (int tl = 0; tl < TILES; ++tl) {
      f32x4 a; a[0] = bias_r[tl][0]; a[1] = bias_r[tl][1];
      a[2] = bias_r[tl][2]; a[3] = bias_r[tl][3];
      acc[tl] = a;
    }

    // ---- x @ W  (A = W^T frags, B = x^T frag) ----
#pragma unroll
    for (int q = 0; q < KX; ++q) {
      short8 bx = pack2(xa[q], xb[q]);
#pragma unroll
      for (int tl = 0; tl < TILES; ++tl)
        acc[tl] = __builtin_amdgcn_mfma_f32_16x16x32_bf16(au[tl][KH + q], bx, acc[tl], 0, 0, 0);
    }

    // ---- h(t-1) @ U ----
    if (t > 0) {
#pragma unroll
      for (int ks = 0; ks < KH; ++ks)
#pragma unroll
        for (int tl = 0; tl < TILES; ++tl)
          acc[tl] = __builtin_amdgcn_mfma_f32_16x16x32_bf16(au[tl][ks], bh[ks], acc[tl], 0, 0, 0);
    }

    // ---- gates: regs 0..3 of each tile are i,f,g,o of ONE unit ----
    unsigned short* hw = hbuf + (size_t)((t + 1) & 1) * HBUF_ELEMS;
    const int brow = bbase + l15;
#pragma unroll
    for (int tl = 0; tl < TILES; ++tl) {
      const float zi = acc[tl][0], zf = acc[tl][1], zg = acc[tl][2], zo = acc[tl][3];
      const float ig = 1.f / (1.f + __expf(-zi));
      const float fg = 1.f / (1.f + __expf(-zf));
      const float gg = fmaxf(zg, 0.f);              // relu candidate
      const float og = 1.f / (1.f + __expf(-zo));
      const float cn = fg * cst[tl] + ig * gg;
      cst[tl] = cn;
      const float h = og * fmaxf(cn, 0.f);          // relu output activation
      const int unit = u0 + tl * 4 + l4;
      hw[(size_t)brow * H_ + unit] = f2bf(h);
      out[((size_t)brow * S_ + t) * H_ + unit] = h;
    }

    // ---- publish: barrier drains all waves' stores into this XCD's L2,
    //      then one agent-scope release store makes them visible ----
    __syncthreads();
    if (tid == 0)
      __hip_atomic_store(myflag, (unsigned)(t + 1), __ATOMIC_RELEASE, __HIP_MEMORY_SCOPE_AGENT);
  }
}

extern "C" void kernel_launch(void* const* d_in, const int* in_sizes, int n_in,
                              void* d_out, int out_size, void* d_ws, size_t ws_size,
                              hipStream_t stream) {
  const float* x = (const float*)d_in[0];
  const float* W = (const float*)d_in[1];
  const float* U = (const float*)d_in[2];
  const float* b = (const float*)d_in[3];
  float* out = (float*)d_out;

  unsigned int*   flags = (unsigned int*)d_ws;                    // 4*8 flags, 64B apart
  unsigned short* hbuf  = (unsigned short*)((char*)d_ws + 4096);  // 2 x 64 x 512 bf16

  hipMemsetAsync(d_ws, 0, 4096, stream);   // zero flags each launch/replay

  lstm_pers<<<dim3(GROUPS * WGPG), dim3(64 * WAVES), 0, stream>>>(x, W, U, b, out, flags, hbuf);
}